// Round 7
// baseline (211.925 us; speedup 1.0000x reference)
//
#include <hip/hip_runtime.h>
#include <cmath>

// ---------------- problem constants ----------------
#define M_ROWS   11520      // 2*5760
#define DIM      512
#define HID      1960
#define HIDP     2048       // padded HID (zeros)
#define KP2      1984       // GEMM2 K-loop bound: 31*64 >= HID, cols [1960,1984) are zero
#define OH       20
#define OW       36
#define LVEC     720        // OH*OW
#define NCH      40         // HID/49
#define BPRIME   16         // M_ROWS / LVEC

typedef unsigned short u16;
typedef __bf16 bf16x8 __attribute__((ext_vector_type(8)));
typedef float  f32x4  __attribute__((ext_vector_type(4)));
typedef unsigned short u16x8 __attribute__((ext_vector_type(8)));

__device__ __forceinline__ u16 f2bf(float f) {
    unsigned u = __float_as_uint(f);
    u += 0x7fffu + ((u >> 16) & 1u);   // RNE
    return (u16)(u >> 16);
}
__device__ __forceinline__ float bf2f(u16 h) {
    return __uint_as_float(((unsigned)h) << 16);
}

__device__ __forceinline__ void gload_lds16(const void* g, void* l) {
    __builtin_amdgcn_global_load_lds(
        (const __attribute__((address_space(1))) void*)g,
        (__attribute__((address_space(3))) void*)l, 16, 0, 0);
}

// ---------------- fused fp32 -> bf16 converts + g2 pad-zeroing (one dispatch) ----------------
#define CVT_XB   5760
#define CVT_W1B  1024
#define CVT_W2B  1024
#define CVT_Z    270       // 11520 rows * 24 cols / (256*4)
__global__ __launch_bounds__(256) void cvt_all(const float* __restrict__ x,
                                               const float* __restrict__ W1,
                                               const float* __restrict__ W2,
                                               u16* __restrict__ xb,
                                               u16* __restrict__ W1b,
                                               u16* __restrict__ W2b,
                                               u16* __restrict__ g2) {
    const int b = blockIdx.x;
    const int tid = threadIdx.x;
    ushort4 o;
    if (b < CVT_XB) {
        int i = (b * 256 + tid) * 4;
        float4 v = *(const float4*)(x + i);
        o.x = f2bf(v.x); o.y = f2bf(v.y); o.z = f2bf(v.z); o.w = f2bf(v.w);
        *(ushort4*)(xb + i) = o;
    } else if (b < CVT_XB + CVT_W1B) {
        int i = ((b - CVT_XB) * 256 + tid) * 4;      // over 2048*512
        if (i < HID * DIM) {
            float4 v = *(const float4*)(W1 + i);
            o.x = f2bf(v.x); o.y = f2bf(v.y); o.z = f2bf(v.z); o.w = f2bf(v.w);
        } else {
            o.x = o.y = o.z = o.w = 0;
        }
        *(ushort4*)(W1b + i) = o;
    } else if (b < CVT_XB + CVT_W1B + CVT_W2B) {
        int i = ((b - CVT_XB - CVT_W1B) * 256 + tid) * 4;   // over 512*2048
        int d = i / HIDP, c = i - d * HIDP;
        if (c < HID) {
            float4 v = *(const float4*)(W2 + (size_t)d * HID + c);
            o.x = f2bf(v.x); o.y = f2bf(v.y); o.z = f2bf(v.z); o.w = f2bf(v.w);
        } else {
            o.x = o.y = o.z = o.w = 0;
        }
        *(ushort4*)(W2b + i) = o;
    } else {
        int i = ((b - CVT_XB - CVT_W1B - CVT_W2B) * 256 + tid) * 4;  // over 11520*24
        int row = i / 24, c = i - row * 24;
        o.x = o.y = o.z = o.w = 0;
        *(ushort4*)(g2 + (size_t)row * HIDP + HID + c) = o;
    }
}

// ---------------- GEMM1: h = x @ W1^T + b1 -> bf16, 256x256 tile ----------------
// M=11520, K=512, N=2048.  Staged-volume model: volume = 2*M*N*K*(1/BM+1/BN);
// 256x256 gives 189 MB vs 128^2's 369 MB -- the invariant that explains why
// every schedule variant (2-bar / ring / 8-phase / forced-occ) sat at 40-52 us
// with MfmaUtil ~19%.  Structure: proven 2-barrier loop.
// 1024 threads = 16 waves (4M x 4N), wave 64x64, acc[4][4].  LDS 64 KB
// (sA 256x64, sB 256x64), 4 gloads/thread/K-step, XOR swizzle both sides.
// Epilogue: quarter-tile (64-row) LDS bounce with block-XOR swizzle ->
// 16B coalesced stores (round-4 validated WRITE_SIZE fix).
__global__ __launch_bounds__(1024) void gemm1_256(const u16* __restrict__ A,
                                                  const u16* __restrict__ B,
                                                  const float* __restrict__ bias,
                                                  u16* __restrict__ C) {
    __shared__ u16 smem[2 * 256 * 64];   // 64 KB: sA then sB
    u16* sA = smem;
    u16* sB = smem + 256 * 64;

    const int tid  = threadIdx.x;
    const int NB   = gridDim.x;          // 360, %8==0
    const int v    = (blockIdx.x & 7) * (NB >> 3) + (blockIdx.x >> 3);
    const int bm   = v >> 3;             // ntn = 8
    const int bn   = v & 7;
    const int lane = tid & 63;
    const int wv   = tid >> 6;           // 0..15
    const int wm   = (wv >> 2) * 64;
    const int wn   = (wv & 3) * 64;
    const int r    = lane & 15;
    const int quad = lane >> 4;

    const size_t Arow0 = (size_t)bm * 256 * DIM;
    const size_t Brow0 = (size_t)bn * 256 * DIM;

    f32x4 acc[4][4] = {};

    for (int kt = 0; kt < DIM; kt += 64) {
        __syncthreads();
#pragma unroll
        for (int i = 0; i < 2; i++) {    // A: 2048 chunks / 1024 threads
            int e   = i * 1024 + tid;
            int row = e >> 3;
            int cg  = (e & 7) ^ (row & 7);
            gload_lds16(A + Arow0 + (size_t)row * DIM + kt + cg * 8, (char*)sA + e * 16);
        }
#pragma unroll
        for (int i = 0; i < 2; i++) {    // B: 2048 chunks / 1024 threads
            int e   = i * 1024 + tid;
            int row = e >> 3;
            int cg  = (e & 7) ^ (row & 7);
            gload_lds16(B + Brow0 + (size_t)row * DIM + kt + cg * 8, (char*)sB + e * 16);
        }
        __syncthreads();
#pragma unroll
        for (int kk = 0; kk < 2; kk++) {
            bf16x8 af[4], bg[4];
#pragma unroll
            for (int m = 0; m < 4; m++) {
                int row = wm + m * 16 + r;
                int c   = (kk * 4 + quad) ^ (row & 7);
                af[m] = *(const bf16x8*)(sA + row * 64 + c * 8);
            }
#pragma unroll
            for (int u = 0; u < 4; u++) {
                int row = wn + u * 16 + r;
                int c   = (kk * 4 + quad) ^ (row & 7);
                bg[u] = *(const bf16x8*)(sB + row * 64 + c * 8);
            }
#pragma unroll
            for (int m = 0; m < 4; m++)
#pragma unroll
                for (int u = 0; u < 4; u++)
                    acc[m][u] = __builtin_amdgcn_mfma_f32_16x16x32_bf16(
                        af[m], bg[u], acc[m][u], 0, 0, 0);
        }
    }

    // epilogue: 4 quarter-tiles of 64 rows, bounced through sA (64x256 u16,
    // block-XOR swizzle: 8-u16 block b at row R lives at b ^ (R&7)).
    const int gn0 = bn * 256;
#pragma unroll
    for (int qt = 0; qt < 4; ++qt) {
        __syncthreads();
        if ((wv >> 2) == qt) {
#pragma unroll
            for (int u = 0; u < 4; u++) {
                int scol = wn + u * 16 + r;
                int gng  = gn0 + scol;
                float bv = (gng < HID) ? bias[gng] : 0.0f;
#pragma unroll
                for (int m = 0; m < 4; m++) {
#pragma unroll
                    for (int q = 0; q < 4; q++) {
                        int srow = m * 16 + quad * 4 + q;
                        smem[srow * 256 + (scol ^ ((srow & 7) << 3))] =
                            f2bf(acc[m][u][q] + bv);
                    }
                }
            }
        }
        __syncthreads();
        // 1024 threads: row = tid>>4 (0..63), 16 u16 each (2 x 16B)
        const int row = tid >> 4;
        const int t16 = tid & 15;
        const int b0  = (t16 * 2) ^ (row & 7);
        const int b1  = (t16 * 2 + 1) ^ (row & 7);
        u16x8 w0 = *(const u16x8*)(smem + row * 256 + b0 * 8);
        u16x8 w1 = *(const u16x8*)(smem + row * 256 + b1 * 8);
        u16* dst = C + (size_t)(bm * 256 + qt * 64 + row) * HIDP + gn0 + t16 * 16;
        *(u16x8*)dst       = w0;
        *(u16x8*)(dst + 8) = w1;
    }
}

// ---------------- GEMM2: out = g2 @ W2^T + b2 -> fp32, 128x128 tile ----------------
// M=11520, K=1984 (ld 2048), N=512.  128x128 cuts staged volume 548 -> 366 MB
// vs the old 128x64.  512 thr = 8 waves (2M x 4N), wave 64x32, acc[4][2].
// 2-barrier structure; direct fp32 stores (full 64B lines).
__global__ __launch_bounds__(512) void gemm2_128(const u16* __restrict__ A,
                                                 const u16* __restrict__ B,
                                                 const float* __restrict__ bias,
                                                 float* __restrict__ C) {
    __shared__ u16 sA[128 * 64];         // 16 KB
    __shared__ u16 sB[128 * 64];         // 16 KB

    const int tid  = threadIdx.x;
    const int NB   = gridDim.x;          // 360, %8==0
    const int v    = (blockIdx.x & 7) * (NB >> 3) + (blockIdx.x >> 3);
    const int bm   = v >> 2;             // ntn = 4
    const int bn   = v & 3;
    const int lane = tid & 63;
    const int wv   = tid >> 6;           // 0..7
    const int wm   = (wv >> 2) * 64;     // 2 wave-rows
    const int wn   = (wv & 3) * 32;      // 4 wave-cols
    const int r    = lane & 15;
    const int quad = lane >> 4;

    const size_t Arow0 = (size_t)bm * 128 * HIDP;
    const size_t Brow0 = (size_t)bn * 128 * HIDP;

    f32x4 acc[4][2] = {};

    for (int kt = 0; kt < KP2; kt += 64) {
        __syncthreads();
#pragma unroll
        for (int i = 0; i < 2; i++) {    // A: 1024 chunks / 512 threads
            int e   = i * 512 + tid;
            int row = e >> 3;
            int cg  = (e & 7) ^ (row & 7);
            gload_lds16(A + Arow0 + (size_t)row * HIDP + kt + cg * 8, (char*)sA + e * 16);
        }
#pragma unroll
        for (int i = 0; i < 2; i++) {    // B: 1024 chunks / 512 threads
            int e   = i * 512 + tid;
            int row = e >> 3;
            int cg  = (e & 7) ^ (row & 7);
            gload_lds16(B + Brow0 + (size_t)row * HIDP + kt + cg * 8, (char*)sB + e * 16);
        }
        __syncthreads();
#pragma unroll
        for (int kk = 0; kk < 2; kk++) {
            bf16x8 af[4], bg[2];
#pragma unroll
            for (int m = 0; m < 4; m++) {
                int row = wm + m * 16 + r;
                int c   = (kk * 4 + quad) ^ (row & 7);
                af[m] = *(const bf16x8*)(sA + row * 64 + c * 8);
            }
#pragma unroll
            for (int u = 0; u < 2; u++) {
                int row = wn + u * 16 + r;
                int c   = (kk * 4 + quad) ^ (row & 7);
                bg[u] = *(const bf16x8*)(sB + row * 64 + c * 8);
            }
#pragma unroll
            for (int m = 0; m < 4; m++)
#pragma unroll
                for (int u = 0; u < 2; u++)
                    acc[m][u] = __builtin_amdgcn_mfma_f32_16x16x32_bf16(
                        af[m], bg[u], acc[m][u], 0, 0, 0);
        }
    }

    const int gm0 = bm * 128 + wm;
    const int gn0 = bn * 128 + wn;
#pragma unroll
    for (int u = 0; u < 2; u++) {
        int gn = gn0 + u * 16 + r;
        float bv = bias[gn];
#pragma unroll
        for (int m = 0; m < 4; m++) {
            int gm = gm0 + m * 16 + quad * 4;
#pragma unroll
            for (int q = 0; q < 4; q++)
                C[(size_t)(gm + q) * DIM + gn] = acc[m][u][q] + bv;
        }
    }
}

// ---------------- mid: fold + normalize + crop + GELU + unfold, fully fused ----------------
// (round-1 version, unchanged -- control)
__global__ __launch_bounds__(512) void mid_fused(const u16* __restrict__ hg,
                                                 u16* __restrict__ g2) {
    __shared__ u16 sh[12 * 20 * 56];   // 13440 u16 = 26880 B
    __shared__ u16 sG[34 * 58];        //  1972 u16 =  3944 B

    const int b   = blockIdx.x;
    const int bp  = b / (NCH * 4);
    const int rr  = b - bp * (NCH * 4);
    const int ch  = rr >> 2;
    const int s   = (rr >> 1) & 1;
    const int xh  = rr & 1;
    const int o0  = s * 10;            // first owned oy
    const int lo  = s * 8;             // first loaded oy
    const int ox0 = xh * 16;           // first loaded ox
    const int n0  = bp * LVEC;
    const int c0  = ch * 49;
    const int c0f = c0 & ~7;           // 16B-aligned channel base
    const int koff = c0 & 7;           // 0..7 (koff + 49 <= 56)
    const int tid = threadIdx.x;

    // phase 0: 12 oy-rows x 20 ox-cols x 7 chunks of 16B, DMA'd to LDS.
    {
        const char* hb = (const char*)(hg + (size_t)(n0 + lo * 36 + ox0) * HIDP + c0f);
        for (int t = tid; t < 12 * 20 * 7; t += 512) {
            int r   = (int)(((unsigned)t * 74899u) >> 19);
            int c   = t - r * 7;
            int loy = (int)(((unsigned)r * 3277u) >> 16);
            int oxl = r - 20 * loy;
            gload_lds16(hb + (size_t)(loy * 36 + oxl) * (HIDP * 2) + c * 16,
                        (char*)sh + t * 16);
        }
    }
    __syncthreads();

    // phase 1: G rows [3*o0, 3*o0+34) x local px [0,58) -> sG
    const int pxl = tid & 63;
    const int rg  = tid >> 6;          // 0..7, wave-uniform
    if (pxl < 58) {
        const int  pxg  = pxl + 54 * xh;              // global px
        const bool pxin = (pxg >= 3) && (pxg <= 110);
        const int  kx0  = pxg % 3;
        int  ct[3];
        bool vx[3];
        int  cx = 0;
#pragma unroll
        for (int dx = 0; dx < 3; dx++) {
            int kx = kx0 + 3 * dx, rx = pxg - kx;
            bool ok = pxin && (kx <= 6) && (rx >= 0) && (rx <= 105);
            vx[dx] = ok;
            ct[dx] = ok ? ((rx / 3) - ox0) * 56 + kx : 0;
            cx += ok ? 1 : 0;
        }
        const float fcx = (cx == 3) ? (1.0f / 3.0f) : ((cx == 2) ? 0.5f : 1.0f);

        for (int pr = rg; pr < 34; pr += 8) {
            int py = 3 * o0 + pr;      // wave-uniform
            float val = 0.0f;
            if (pxin && py >= 3 && py <= 62) {
                int ky0 = py % 3;
                float sum = 0.0f;
                int cy = 0;
#pragma unroll
                for (int dy = 0; dy < 3; dy++) {
                    int ky = ky0 + 3 * dy, ry = py - ky;   // uniform
                    if (ky <= 6 && ry >= 0 && ry <= 57) {  // uniform branch
                        int rt = (ry / 3 - lo) * (20 * 56) + ky * 7 + koff;
                        cy++;
                        float v0 = bf2f(sh[rt + ct[0]]);
                        float v1 = bf2f(sh[rt + ct[1]]);
                        float v2 = bf2f(sh[rt + ct[2]]);
                        sum += vx[0] ? v0 : 0.0f;
                        sum += vx[1] ? v1 : 0.0f;
                        sum += vx[2] ? v2 : 0.0f;
                    }
                }
                float fcy = (cy == 3) ? (1.0f / 3.0f) : ((cy == 2) ? 0.5f : 1.0f);
                float m = sum * fcx * fcy;
                val = 0.5f * m * (1.0f + erff(m * 0.70710678118654752f));  // exact gelu
            }
            sG[pr * 58 + pxl] = f2bf(val);
        }
    }
    __syncthreads();

    // phase 2: unfold sG -> g2 (magic-mul indices, no LUTs)
    {
        u16* g2row = g2 + (size_t)(n0 + o0 * 36 + 18 * xh) * HIDP + c0;
        for (int j = tid; j < 10 * 18 * 49; j += 512) {
            int l2 = (int)(((unsigned)j * 42800u) >> 21);
            int k  = j - l2 * 49;
            int oy = (int)(((unsigned)l2 * 57u) >> 10);
            int ox = l2 - 18 * oy;
            int ky = (int)(((unsigned)k * 37u) >> 8);
            int kx = k - 7 * ky;
            g2row[(size_t)(oy * 36 + ox) * HIDP + k] =
                sG[(3 * oy + ky) * 58 + 3 * ox + kx];
        }
    }
}

// ---------------- launch ----------------
extern "C" void kernel_launch(void* const* d_in, const int* in_sizes, int n_in,
                              void* d_out, int out_size, void* d_ws, size_t ws_size,
                              hipStream_t stream) {
    (void)in_sizes; (void)n_in; (void)out_size; (void)ws_size;
    const float* x  = (const float*)d_in[0];
    const float* W1 = (const float*)d_in[1];
    const float* b1 = (const float*)d_in[2];
    const float* W2 = (const float*)d_in[3];
    const float* b2 = (const float*)d_in[4];
    float* out = (float*)d_out;

    char* ws = (char*)d_ws;
    u16* xb  = (u16*)(ws);                       // 11520*512*2  = 11,796,480
    u16* W1b = (u16*)(ws + 11796480);            // 2048*512*2   =  2,097,152
    u16* W2b = (u16*)(ws + 13893632);            // 512*2048*2   =  2,097,152
    u16* hg  = (u16*)(ws + 15990784);            // 11520*2048*2 = 47,185,920
    u16* g2  = (u16*)(ws + 63176704);            // 11520*2048*2 = 47,185,920 (total 110 MB)

    // converts + g2 pad-zeroing (single dispatch)
    cvt_all<<<CVT_XB + CVT_W1B + CVT_W2B + CVT_Z, 256, 0, stream>>>(
        x, W1, W2, xb, W1b, W2b, g2);

    // GEMM1: 256x256 tiles (staged volume 189 MB), grid 45*8 = 360, 1024 thr
    gemm1_256<<<(M_ROWS / 256) * (HIDP / 256), 1024, 0, stream>>>(xb, W1b, b1, hg);

    // middle: fold/normalize/gelu/unfold fused, hg -> g2 (G stays in LDS)
    mid_fused<<<BPRIME * NCH * 4, 512, 0, stream>>>(hg, g2);

    // GEMM2: 128x128 tiles (staged volume 366 MB), grid 90*4 = 360, 512 thr
    gemm2_128<<<(M_ROWS / 128) * (DIM / 128), 512, 0, stream>>>(g2, W2b, b2, out);
}

// Round 8
// 190.498 us; speedup vs baseline: 1.1125x; 1.1125x over previous
//
#include <hip/hip_runtime.h>
#include <cmath>

// ---------------- problem constants ----------------
#define M_ROWS   11520      // 2*5760
#define DIM      512
#define HID      1960
#define HIDP     2048       // padded HID (zeros)
#define KP2      1984       // GEMM2 K-loop bound: 31*64 >= HID, cols [1960,1984) are zero
#define OH       20
#define OW       36
#define LVEC     720        // OH*OW
#define NCH      40         // HID/49
#define BPRIME   16         // M_ROWS / LVEC

typedef unsigned short u16;
typedef __bf16 bf16x8 __attribute__((ext_vector_type(8)));
typedef float  f32x4  __attribute__((ext_vector_type(4)));
typedef unsigned short u16x8 __attribute__((ext_vector_type(8)));

__device__ __forceinline__ u16 f2bf(float f) {
    unsigned u = __float_as_uint(f);
    u += 0x7fffu + ((u >> 16) & 1u);   // RNE
    return (u16)(u >> 16);
}
__device__ __forceinline__ float bf2f(u16 h) {
    return __uint_as_float(((unsigned)h) << 16);
}

__device__ __forceinline__ void gload_lds16(const void* g, void* l) {
    __builtin_amdgcn_global_load_lds(
        (const __attribute__((address_space(1))) void*)g,
        (__attribute__((address_space(3))) void*)l, 16, 0, 0);
}

// ---------------- fused fp32 -> bf16 converts + g2 pad-zeroing (one dispatch) ----------------
#define CVT_XB   5760
#define CVT_W1B  1024
#define CVT_W2B  1024
#define CVT_Z    270       // 11520 rows * 24 cols / (256*4)
__global__ __launch_bounds__(256) void cvt_all(const float* __restrict__ x,
                                               const float* __restrict__ W1,
                                               const float* __restrict__ W2,
                                               u16* __restrict__ xb,
                                               u16* __restrict__ W1b,
                                               u16* __restrict__ W2b,
                                               u16* __restrict__ g2) {
    const int b = blockIdx.x;
    const int tid = threadIdx.x;
    ushort4 o;
    if (b < CVT_XB) {
        int i = (b * 256 + tid) * 4;
        float4 v = *(const float4*)(x + i);
        o.x = f2bf(v.x); o.y = f2bf(v.y); o.z = f2bf(v.z); o.w = f2bf(v.w);
        *(ushort4*)(xb + i) = o;
    } else if (b < CVT_XB + CVT_W1B) {
        int i = ((b - CVT_XB) * 256 + tid) * 4;      // over 2048*512
        if (i < HID * DIM) {
            float4 v = *(const float4*)(W1 + i);
            o.x = f2bf(v.x); o.y = f2bf(v.y); o.z = f2bf(v.z); o.w = f2bf(v.w);
        } else {
            o.x = o.y = o.z = o.w = 0;
        }
        *(ushort4*)(W1b + i) = o;
    } else if (b < CVT_XB + CVT_W1B + CVT_W2B) {
        int i = ((b - CVT_XB - CVT_W1B) * 256 + tid) * 4;   // over 512*2048
        int d = i / HIDP, c = i - d * HIDP;
        if (c < HID) {
            float4 v = *(const float4*)(W2 + (size_t)d * HID + c);
            o.x = f2bf(v.x); o.y = f2bf(v.y); o.z = f2bf(v.z); o.w = f2bf(v.w);
        } else {
            o.x = o.y = o.z = o.w = 0;
        }
        *(ushort4*)(W2b + i) = o;
    } else {
        int i = ((b - CVT_XB - CVT_W1B - CVT_W2B) * 256 + tid) * 4;  // over 11520*24
        int row = i / 24, c = i - row * 24;
        o.x = o.y = o.z = o.w = 0;
        *(ushort4*)(g2 + (size_t)row * HIDP + HID + c) = o;
    }
}

// ---------------- bf16 NT-GEMM: C[m,n] = sum_k A[m,k]*B[n,k] + bias[n] ----------------
// Round-1 proven structure (the empirical optimum over 6 tried variants:
// ring-3, 8-phase, 256x128, 256^2, forced-occupancy all regressed; time
// correlates inversely with block count -> 128-row tiles, max blocks).
// 128(M) x BN(N) tile, BK=64, 512 threads = 8 waves (4M x 2N), wave 32 x BN/2
// via mfma_f32_16x16x32_bf16.  global_load_lds width-16 staging, XOR swizzle
// on the GLOBAL side so ds_read_b128 is conflict-free.
//
// OUT_BF16 epilogue: LDS-bounce (stride 136) -> 4x16B coalesced stores per
// thread.  The ONLY validated improvement from rounds 2-7: fixes the ~1.5x
// partial-line write amplification of scalar u16 stores (WRITE_SIZE 75.5 ->
// 46.1 MB, matched prediction on two independent kernels).
//
// XCD-locality block swizzle: v = (blockIdx&7)*(NB/8) + (blockIdx>>3) gives
// each XCD a contiguous strip of bm values x all bn.  Requires grid % 8 == 0.
template <int OUT_BF16, int BN>
__global__ __launch_bounds__(512) void gemm_bt(const u16* __restrict__ A,
                                               const u16* __restrict__ B,
                                               const float* __restrict__ bias,
                                               int biasN, void* __restrict__ Cout,
                                               int N, int K, int ldk) {
    constexpr int WN  = BN / 2;      // wave N extent
    constexpr int NU  = WN / 16;     // acc tiles along N (4 or 2)
    constexpr int BCH = BN * 8;      // B-tile 16B chunks (1024 or 512)
    // shared sizing: tiles need 128*64 + BN*64; bf16 bounce needs 128*136
    constexpr int SMEMU = OUT_BF16 ? (128 * 136) : (128 * 64 + BN * 64);

    __shared__ u16 smem[SMEMU];
    u16* sA = smem;                  // 128 x 64
    u16* sB = smem + 128 * 64;       // BN x 64

    const int tid  = threadIdx.x;
    const int ntn  = N / BN;
    const int NB   = gridDim.x;
    const int v    = (blockIdx.x & 7) * (NB >> 3) + (blockIdx.x >> 3);
    const int bm   = v / ntn;
    const int bn   = v - bm * ntn;
    const int lane = tid & 63;
    const int wv   = tid >> 6;       // 0..7
    const int wm   = (wv >> 1) * 32; // 4 wave-rows of 32
    const int wn   = (wv & 1) * WN;  // 2 wave-cols
    const int r    = lane & 15;
    const int quad = lane >> 4;

    const size_t Arow0 = (size_t)bm * 128 * ldk;
    const size_t Brow0 = (size_t)bn * BN * ldk;

    f32x4 acc[2][NU] = {};

    for (int kt = 0; kt < K; kt += 64) {
        __syncthreads();
#pragma unroll
        for (int i = 0; i < 2; i++) {          // A: 1024 chunks / 512 threads
            int e   = i * 512 + tid;
            int row = e >> 3;
            int cp  = e & 7;
            int cg  = cp ^ (row & 7);
            gload_lds16(A + Arow0 + (size_t)row * ldk + kt + cg * 8, (char*)sA + e * 16);
        }
#pragma unroll
        for (int i = 0; i < BCH / 512; i++) {  // B: BCH chunks / 512 threads
            int e   = i * 512 + tid;
            int row = e >> 3;
            int cp  = e & 7;
            int cg  = cp ^ (row & 7);
            gload_lds16(B + Brow0 + (size_t)row * ldk + kt + cg * 8, (char*)sB + e * 16);
        }
        __syncthreads();
#pragma unroll
        for (int kk = 0; kk < 2; kk++) {
            bf16x8 af[2], bg[NU];
#pragma unroll
            for (int t = 0; t < 2; t++) {
                int row = wm + t * 16 + r;
                int c   = (kk * 4 + quad) ^ (row & 7);
                af[t] = *(const bf16x8*)(sA + row * 64 + c * 8);
            }
#pragma unroll
            for (int u = 0; u < NU; u++) {
                int row = wn + u * 16 + r;
                int c   = (kk * 4 + quad) ^ (row & 7);
                bg[u] = *(const bf16x8*)(sB + row * 64 + c * 8);
            }
#pragma unroll
            for (int t = 0; t < 2; t++)
#pragma unroll
                for (int u = 0; u < NU; u++)
                    acc[t][u] = __builtin_amdgcn_mfma_f32_16x16x32_bf16(
                        af[t], bg[u], acc[t][u], 0, 0, 0);
        }
    }

    // epilogue: C/D layout col = lane&15 (n), row = quad*4+q (m)
    if constexpr (OUT_BF16) {
        static_assert(BN == 128, "bounce assumes 128x128 tile");
        __syncthreads();                 // all waves done reading sA/sB
        // pack C-tile (128 x 128 bf16, stride 136) into smem
#pragma unroll
        for (int u = 0; u < NU; u++) {
            int scol = wn + u * 16 + r;
            int gng  = bn * BN + scol;
            float bv = (gng < biasN) ? bias[gng] : 0.0f;
#pragma unroll
            for (int t = 0; t < 2; t++) {
                int srow = wm + t * 16 + quad * 4;
#pragma unroll
                for (int q = 0; q < 4; q++)
                    smem[(srow + q) * 136 + scol] = f2bf(acc[t][u][q] + bv);
            }
        }
        __syncthreads();
        // 512 threads, 4 per row: each stores 64 B contiguous (4 x 16B);
        // consecutive t4 cover the full 256-B row -> write-combine merges
        // to full lines (round-4 validated: WRITE_SIZE ~= ideal).
        const int row = tid >> 2;        // 0..127
        const int t4  = tid & 3;
        const u16* src = smem + row * 136 + t4 * 32;
        u16* dst = (u16*)Cout + (size_t)(bm * 128 + row) * N + bn * BN + t4 * 32;
#pragma unroll
        for (int j = 0; j < 4; j++)
            *(u16x8*)(dst + j * 8) = *(const u16x8*)(src + j * 8);
    } else {
        const int gm0 = bm * 128 + wm;
        const int gn0 = bn * BN + wn;
#pragma unroll
        for (int u = 0; u < NU; u++) {
            int gn = gn0 + u * 16 + r;
            float bv = (gn < biasN) ? bias[gn] : 0.0f;
#pragma unroll
            for (int t = 0; t < 2; t++) {
                int gm = gm0 + t * 16 + quad * 4;
#pragma unroll
                for (int q = 0; q < 4; q++)
                    ((float*)Cout)[(size_t)(gm + q) * N + gn] = acc[t][u][q] + bv;
            }
        }
    }
}

// ---------------- mid: fold + normalize + crop + GELU + unfold, fully fused ----------------
// (round-1 version, unchanged -- control)
__global__ __launch_bounds__(512) void mid_fused(const u16* __restrict__ hg,
                                                 u16* __restrict__ g2) {
    __shared__ u16 sh[12 * 20 * 56];   // 13440 u16 = 26880 B
    __shared__ u16 sG[34 * 58];        //  1972 u16 =  3944 B

    const int b   = blockIdx.x;
    const int bp  = b / (NCH * 4);
    const int rr  = b - bp * (NCH * 4);
    const int ch  = rr >> 2;
    const int s   = (rr >> 1) & 1;
    const int xh  = rr & 1;
    const int o0  = s * 10;            // first owned oy
    const int lo  = s * 8;             // first loaded oy
    const int ox0 = xh * 16;           // first loaded ox
    const int n0  = bp * LVEC;
    const int c0  = ch * 49;
    const int c0f = c0 & ~7;           // 16B-aligned channel base
    const int koff = c0 & 7;           // 0..7 (koff + 49 <= 56)
    const int tid = threadIdx.x;

    // phase 0: 12 oy-rows x 20 ox-cols x 7 chunks of 16B, DMA'd to LDS.
    {
        const char* hb = (const char*)(hg + (size_t)(n0 + lo * 36 + ox0) * HIDP + c0f);
        for (int t = tid; t < 12 * 20 * 7; t += 512) {
            int r   = (int)(((unsigned)t * 74899u) >> 19);
            int c   = t - r * 7;
            int loy = (int)(((unsigned)r * 3277u) >> 16);
            int oxl = r - 20 * loy;
            gload_lds16(hb + (size_t)(loy * 36 + oxl) * (HIDP * 2) + c * 16,
                        (char*)sh + t * 16);
        }
    }
    __syncthreads();

    // phase 1: G rows [3*o0, 3*o0+34) x local px [0,58) -> sG
    const int pxl = tid & 63;
    const int rg  = tid >> 6;          // 0..7, wave-uniform
    if (pxl < 58) {
        const int  pxg  = pxl + 54 * xh;              // global px
        const bool pxin = (pxg >= 3) && (pxg <= 110);
        const int  kx0  = pxg % 3;
        int  ct[3];
        bool vx[3];
        int  cx = 0;
#pragma unroll
        for (int dx = 0; dx < 3; dx++) {
            int kx = kx0 + 3 * dx, rx = pxg - kx;
            bool ok = pxin && (kx <= 6) && (rx >= 0) && (rx <= 105);
            vx[dx] = ok;
            ct[dx] = ok ? ((rx / 3) - ox0) * 56 + kx : 0;
            cx += ok ? 1 : 0;
        }
        const float fcx = (cx == 3) ? (1.0f / 3.0f) : ((cx == 2) ? 0.5f : 1.0f);

        for (int pr = rg; pr < 34; pr += 8) {
            int py = 3 * o0 + pr;      // wave-uniform
            float val = 0.0f;
            if (pxin && py >= 3 && py <= 62) {
                int ky0 = py % 3;
                float sum = 0.0f;
                int cy = 0;
#pragma unroll
                for (int dy = 0; dy < 3; dy++) {
                    int ky = ky0 + 3 * dy, ry = py - ky;   // uniform
                    if (ky <= 6 && ry >= 0 && ry <= 57) {  // uniform branch
                        int rt = (ry / 3 - lo) * (20 * 56) + ky * 7 + koff;
                        cy++;
                        float v0 = bf2f(sh[rt + ct[0]]);
                        float v1 = bf2f(sh[rt + ct[1]]);
                        float v2 = bf2f(sh[rt + ct[2]]);
                        sum += vx[0] ? v0 : 0.0f;
                        sum += vx[1] ? v1 : 0.0f;
                        sum += vx[2] ? v2 : 0.0f;
                    }
                }
                float fcy = (cy == 3) ? (1.0f / 3.0f) : ((cy == 2) ? 0.5f : 1.0f);
                float m = sum * fcx * fcy;
                val = 0.5f * m * (1.0f + erff(m * 0.70710678118654752f));  // exact gelu
            }
            sG[pr * 58 + pxl] = f2bf(val);
        }
    }
    __syncthreads();

    // phase 2: unfold sG -> g2 (magic-mul indices, no LUTs)
    {
        u16* g2row = g2 + (size_t)(n0 + o0 * 36 + 18 * xh) * HIDP + c0;
        for (int j = tid; j < 10 * 18 * 49; j += 512) {
            int l2 = (int)(((unsigned)j * 42800u) >> 21);
            int k  = j - l2 * 49;
            int oy = (int)(((unsigned)l2 * 57u) >> 10);
            int ox = l2 - 18 * oy;
            int ky = (int)(((unsigned)k * 37u) >> 8);
            int kx = k - 7 * ky;
            g2row[(size_t)(oy * 36 + ox) * HIDP + k] =
                sG[(3 * oy + ky) * 58 + 3 * ox + kx];
        }
    }
}

// ---------------- launch ----------------
extern "C" void kernel_launch(void* const* d_in, const int* in_sizes, int n_in,
                              void* d_out, int out_size, void* d_ws, size_t ws_size,
                              hipStream_t stream) {
    (void)in_sizes; (void)n_in; (void)out_size; (void)ws_size;
    const float* x  = (const float*)d_in[0];
    const float* W1 = (const float*)d_in[1];
    const float* b1 = (const float*)d_in[2];
    const float* W2 = (const float*)d_in[3];
    const float* b2 = (const float*)d_in[4];
    float* out = (float*)d_out;

    char* ws = (char*)d_ws;
    u16* xb  = (u16*)(ws);                       // 11520*512*2  = 11,796,480
    u16* W1b = (u16*)(ws + 11796480);            // 2048*512*2   =  2,097,152
    u16* W2b = (u16*)(ws + 13893632);            // 512*2048*2   =  2,097,152
    u16* hg  = (u16*)(ws + 15990784);            // 11520*2048*2 = 47,185,920
    u16* g2  = (u16*)(ws + 63176704);            // 11520*2048*2 = 47,185,920 (total 110 MB)

    // converts + g2 pad-zeroing (single dispatch)
    cvt_all<<<CVT_XB + CVT_W1B + CVT_W2B + CVT_Z, 256, 0, stream>>>(
        x, W1, W2, xb, W1b, W2b, g2);

    // GEMM1: h = x @ W1^T + b1 -> bf16 (11520 x 2048), 128x128 tiles,
    // grid 90*16 = 1440 (block-count optimum), bounce epilogue.
    gemm_bt<1, 128><<<(M_ROWS / 128) * (HIDP / 128), 512, 0, stream>>>(
        xb, W1b, b1, HID, (void*)hg, HIDP, DIM, DIM);

    // middle: fold/normalize/gelu/unfold fused, hg -> g2 (G stays in LDS)
    mid_fused<<<BPRIME * NCH * 4, 512, 0, stream>>>(hg, g2);

    // GEMM2: out = g2 @ W2^T + b2 -> fp32 (11520 x 512), 128x64 tiles,
    // K trimmed to 1984 (g2 cols [1960,1984) zero-filled by cvt_all).
    gemm_bt<0, 64><<<(M_ROWS / 128) * (DIM / 64), 512, 0, stream>>>(
        g2, W2b, b2, DIM, (void*)out, DIM, KP2, HIDP);
}

// Round 9
// 187.509 us; speedup vs baseline: 1.1302x; 1.0159x over previous
//
#include <hip/hip_runtime.h>
#include <cmath>

// ---------------- problem constants ----------------
#define M_ROWS   11520      // 2*5760
#define DIM      512
#define HID      1960
#define HIDP     2048       // padded HID (zeros)
#define KP2      1984       // GEMM2 K-loop bound: 31*64 >= HID, cols [1960,1984) are zero
#define OH       20
#define OW       36
#define LVEC     720        // OH*OW
#define NCH      40         // HID/49
#define BPRIME   16         // M_ROWS / LVEC

typedef unsigned short u16;
typedef __bf16 bf16x8 __attribute__((ext_vector_type(8)));
typedef float  f32x4  __attribute__((ext_vector_type(4)));

__device__ __forceinline__ u16 f2bf(float f) {
    unsigned u = __float_as_uint(f);
    u += 0x7fffu + ((u >> 16) & 1u);   // RNE
    return (u16)(u >> 16);
}
__device__ __forceinline__ float bf2f(u16 h) {
    return __uint_as_float(((unsigned)h) << 16);
}

__device__ __forceinline__ void gload_lds16(const void* g, void* l) {
    __builtin_amdgcn_global_load_lds(
        (const __attribute__((address_space(1))) void*)g,
        (__attribute__((address_space(3))) void*)l, 16, 0, 0);
}

// ---------------- fused fp32 -> bf16 converts + g2 pad-zeroing (one dispatch) ----------------
#define CVT_XB   5760
#define CVT_W1B  1024
#define CVT_W2B  1024
#define CVT_Z    270       // 11520 rows * 24 cols / (256*4)
__global__ __launch_bounds__(256) void cvt_all(const float* __restrict__ x,
                                               const float* __restrict__ W1,
                                               const float* __restrict__ W2,
                                               u16* __restrict__ xb,
                                               u16* __restrict__ W1b,
                                               u16* __restrict__ W2b,
                                               u16* __restrict__ g2) {
    const int b = blockIdx.x;
    const int tid = threadIdx.x;
    ushort4 o;
    if (b < CVT_XB) {
        int i = (b * 256 + tid) * 4;
        float4 v = *(const float4*)(x + i);
        o.x = f2bf(v.x); o.y = f2bf(v.y); o.z = f2bf(v.z); o.w = f2bf(v.w);
        *(ushort4*)(xb + i) = o;
    } else if (b < CVT_XB + CVT_W1B) {
        int i = ((b - CVT_XB) * 256 + tid) * 4;      // over 2048*512
        if (i < HID * DIM) {
            float4 v = *(const float4*)(W1 + i);
            o.x = f2bf(v.x); o.y = f2bf(v.y); o.z = f2bf(v.z); o.w = f2bf(v.w);
        } else {
            o.x = o.y = o.z = o.w = 0;
        }
        *(ushort4*)(W1b + i) = o;
    } else if (b < CVT_XB + CVT_W1B + CVT_W2B) {
        int i = ((b - CVT_XB - CVT_W1B) * 256 + tid) * 4;   // over 512*2048
        int d = i / HIDP, c = i - d * HIDP;
        if (c < HID) {
            float4 v = *(const float4*)(W2 + (size_t)d * HID + c);
            o.x = f2bf(v.x); o.y = f2bf(v.y); o.z = f2bf(v.z); o.w = f2bf(v.w);
        } else {
            o.x = o.y = o.z = o.w = 0;
        }
        *(ushort4*)(W2b + i) = o;
    } else {
        int i = ((b - CVT_XB - CVT_W1B - CVT_W2B) * 256 + tid) * 4;  // over 11520*24
        int row = i / 24, c = i - row * 24;
        o.x = o.y = o.z = o.w = 0;
        *(ushort4*)(g2 + (size_t)row * HIDP + HID + c) = o;
    }
}

// ---------------- GEMM1: h = x @ W1^T + b1 -> bf16, 128x64 tile / 256 threads ----------------
// M=11520, K=512, N=2048.  Independent-blocks experiment: 256-thread blocks
// (4 waves of 32x64, acc[2][4] -- per-wave MFMA density preserved at 16/step),
// 24 KB LDS -> 6 blocks/CU (6 independent drain/compute groups vs 4 with
// 512-thr blocks; 6 outstanding gloads/thread during the drain).  Per-block
// MFMA per K-step (~80 SIMD-cyc/wave) is tiny vs the ~1000-1500-cyc stage
// drain, so overlap across INDEPENDENT blocks is the only latency hider
// (m114); this raises its capacity 1.5x.  Main-loop structure: the proven
// round-1 2-barrier loop, untouched.  Scalar bf16 epilogue (the round-8
// bounce REGRESSED: writes were already latency-hidden).
__global__ __launch_bounds__(256) void gemm1_sm(const u16* __restrict__ A,
                                                const u16* __restrict__ B,
                                                const float* __restrict__ bias,
                                                u16* __restrict__ C) {
    __shared__ u16 sA[128 * 64];     // 16 KB
    __shared__ u16 sB[64 * 64];      //  8 KB

    const int tid  = threadIdx.x;
    const int NB   = gridDim.x;      // 2880, %8==0
    const int v    = (blockIdx.x & 7) * (NB >> 3) + (blockIdx.x >> 3);
    const int bm   = v >> 5;         // ntn = 32
    const int bn   = v & 31;
    const int lane = tid & 63;
    const int wv   = tid >> 6;       // 0..3
    const int wm   = wv * 32;        // 4 wave-rows of 32, full 64 N per wave
    const int r    = lane & 15;
    const int quad = lane >> 4;

    const size_t Arow0 = (size_t)bm * 128 * DIM;
    const size_t Brow0 = (size_t)bn * 64 * DIM;

    f32x4 acc[2][4] = {};

    for (int kt = 0; kt < DIM; kt += 64) {
        __syncthreads();
#pragma unroll
        for (int i = 0; i < 4; i++) {        // A: 1024 chunks / 256 threads
            int e   = i * 256 + tid;
            int row = e >> 3;
            int cg  = (e & 7) ^ (row & 7);
            gload_lds16(A + Arow0 + (size_t)row * DIM + kt + cg * 8, (char*)sA + e * 16);
        }
#pragma unroll
        for (int i = 0; i < 2; i++) {        // B: 512 chunks / 256 threads
            int e   = i * 256 + tid;
            int row = e >> 3;
            int cg  = (e & 7) ^ (row & 7);
            gload_lds16(B + Brow0 + (size_t)row * DIM + kt + cg * 8, (char*)sB + e * 16);
        }
        __syncthreads();
#pragma unroll
        for (int kk = 0; kk < 2; kk++) {
            bf16x8 af[2], bg[4];
#pragma unroll
            for (int t = 0; t < 2; t++) {
                int row = wm + t * 16 + r;
                int c   = (kk * 4 + quad) ^ (row & 7);
                af[t] = *(const bf16x8*)(sA + row * 64 + c * 8);
            }
#pragma unroll
            for (int u = 0; u < 4; u++) {
                int row = u * 16 + r;
                int c   = (kk * 4 + quad) ^ (row & 7);
                bg[u] = *(const bf16x8*)(sB + row * 64 + c * 8);
            }
#pragma unroll
            for (int t = 0; t < 2; t++)
#pragma unroll
                for (int u = 0; u < 4; u++)
                    acc[t][u] = __builtin_amdgcn_mfma_f32_16x16x32_bf16(
                        af[t], bg[u], acc[t][u], 0, 0, 0);
        }
    }

    // epilogue: C/D layout col = lane&15 (n), row = quad*4+q (m); scalar u16
    const int gm0 = bm * 128 + wm;
    const int gn0 = bn * 64;
#pragma unroll
    for (int u = 0; u < 4; u++) {
        int gn = gn0 + u * 16 + r;
        float bv = (gn < HID) ? bias[gn] : 0.0f;
#pragma unroll
        for (int t = 0; t < 2; t++) {
            int gm = gm0 + t * 16 + quad * 4;
#pragma unroll
            for (int q = 0; q < 4; q++)
                C[(size_t)(gm + q) * HIDP + gn] = f2bf(acc[t][u][q] + bv);
        }
    }
}

// ---------------- GEMM2: round-1 proven 2-barrier kernel (control) ----------------
// out = g2 @ W2^T + b2 -> fp32 (11520 x 512), 128x64 tile, BK=64, 512 thr =
// 8 waves (4M x 2N) of 32x32, K trimmed to 1984.
__global__ __launch_bounds__(512) void gemm2_bt(const u16* __restrict__ A,
                                                const u16* __restrict__ B,
                                                const float* __restrict__ bias,
                                                float* __restrict__ C) {
    __shared__ u16 sA[128 * 64];
    __shared__ u16 sB[64 * 64];

    const int tid  = threadIdx.x;
    const int NB   = gridDim.x;          // 720, %8==0
    const int v    = (blockIdx.x & 7) * (NB >> 3) + (blockIdx.x >> 3);
    const int bm   = v >> 3;             // ntn = 8
    const int bn   = v & 7;
    const int lane = tid & 63;
    const int wv   = tid >> 6;
    const int wm   = (wv >> 1) * 32;
    const int wn   = (wv & 1) * 32;
    const int r    = lane & 15;
    const int quad = lane >> 4;

    const size_t Arow0 = (size_t)bm * 128 * HIDP;
    const size_t Brow0 = (size_t)bn * 64 * HIDP;

    f32x4 acc[2][2] = {};

    for (int kt = 0; kt < KP2; kt += 64) {
        __syncthreads();
#pragma unroll
        for (int i = 0; i < 2; i++) {    // A: 1024 chunks / 512 threads
            int e   = i * 512 + tid;
            int row = e >> 3;
            int cg  = (e & 7) ^ (row & 7);
            gload_lds16(A + Arow0 + (size_t)row * HIDP + kt + cg * 8, (char*)sA + e * 16);
        }
        {                                // B: 512 chunks / 512 threads
            int row = tid >> 3;
            int cg  = (tid & 7) ^ (row & 7);
            gload_lds16(B + Brow0 + (size_t)row * HIDP + kt + cg * 8, (char*)sB + tid * 16);
        }
        __syncthreads();
#pragma unroll
        for (int kk = 0; kk < 2; kk++) {
            bf16x8 af[2], bg[2];
#pragma unroll
            for (int m = 0; m < 2; m++) {
                int row = wm + m * 16 + r;
                int c   = (kk * 4 + quad) ^ (row & 7);
                af[m] = *(const bf16x8*)(sA + row * 64 + c * 8);
            }
#pragma unroll
            for (int u = 0; u < 2; u++) {
                int row = wn + u * 16 + r;
                int c   = (kk * 4 + quad) ^ (row & 7);
                bg[u] = *(const bf16x8*)(sB + row * 64 + c * 8);
            }
#pragma unroll
            for (int m = 0; m < 2; m++)
#pragma unroll
                for (int u = 0; u < 2; u++)
                    acc[m][u] = __builtin_amdgcn_mfma_f32_16x16x32_bf16(
                        af[m], bg[u], acc[m][u], 0, 0, 0);
        }
    }

    const int gm0 = bm * 128 + wm;
    const int gn0 = bn * 64 + wn;
#pragma unroll
    for (int u = 0; u < 2; u++) {
        int gn = gn0 + u * 16 + r;
        float bv = bias[gn];
#pragma unroll
        for (int m = 0; m < 2; m++) {
            int gm = gm0 + m * 16 + quad * 4;
#pragma unroll
            for (int q = 0; q < 4; q++)
                C[(size_t)(gm + q) * DIM + gn] = acc[m][u][q] + bv;
        }
    }
}

// ---------------- mid: fold + normalize + crop + GELU + unfold, fully fused ----------------
// (round-1 version, unchanged -- control)
__global__ __launch_bounds__(512) void mid_fused(const u16* __restrict__ hg,
                                                 u16* __restrict__ g2) {
    __shared__ u16 sh[12 * 20 * 56];   // 13440 u16 = 26880 B
    __shared__ u16 sG[34 * 58];        //  1972 u16 =  3944 B

    const int b   = blockIdx.x;
    const int bp  = b / (NCH * 4);
    const int rr  = b - bp * (NCH * 4);
    const int ch  = rr >> 2;
    const int s   = (rr >> 1) & 1;
    const int xh  = rr & 1;
    const int o0  = s * 10;            // first owned oy
    const int lo  = s * 8;             // first loaded oy
    const int ox0 = xh * 16;           // first loaded ox
    const int n0  = bp * LVEC;
    const int c0  = ch * 49;
    const int c0f = c0 & ~7;           // 16B-aligned channel base
    const int koff = c0 & 7;           // 0..7 (koff + 49 <= 56)
    const int tid = threadIdx.x;

    // phase 0: 12 oy-rows x 20 ox-cols x 7 chunks of 16B, DMA'd to LDS.
    {
        const char* hb = (const char*)(hg + (size_t)(n0 + lo * 36 + ox0) * HIDP + c0f);
        for (int t = tid; t < 12 * 20 * 7; t += 512) {
            int r   = (int)(((unsigned)t * 74899u) >> 19);
            int c   = t - r * 7;
            int loy = (int)(((unsigned)r * 3277u) >> 16);
            int oxl = r - 20 * loy;
            gload_lds16(hb + (size_t)(loy * 36 + oxl) * (HIDP * 2) + c * 16,
                        (char*)sh + t * 16);
        }
    }
    __syncthreads();

    // phase 1: G rows [3*o0, 3*o0+34) x local px [0,58) -> sG
    const int pxl = tid & 63;
    const int rg  = tid >> 6;          // 0..7, wave-uniform
    if (pxl < 58) {
        const int  pxg  = pxl + 54 * xh;              // global px
        const bool pxin = (pxg >= 3) && (pxg <= 110);
        const int  kx0  = pxg % 3;
        int  ct[3];
        bool vx[3];
        int  cx = 0;
#pragma unroll
        for (int dx = 0; dx < 3; dx++) {
            int kx = kx0 + 3 * dx, rx = pxg - kx;
            bool ok = pxin && (kx <= 6) && (rx >= 0) && (rx <= 105);
            vx[dx] = ok;
            ct[dx] = ok ? ((rx / 3) - ox0) * 56 + kx : 0;
            cx += ok ? 1 : 0;
        }
        const float fcx = (cx == 3) ? (1.0f / 3.0f) : ((cx == 2) ? 0.5f : 1.0f);

        for (int pr = rg; pr < 34; pr += 8) {
            int py = 3 * o0 + pr;      // wave-uniform
            float val = 0.0f;
            if (pxin && py >= 3 && py <= 62) {
                int ky0 = py % 3;
                float sum = 0.0f;
                int cy = 0;
#pragma unroll
                for (int dy = 0; dy < 3; dy++) {
                    int ky = ky0 + 3 * dy, ry = py - ky;   // uniform
                    if (ky <= 6 && ry >= 0 && ry <= 57) {  // uniform branch
                        int rt = (ry / 3 - lo) * (20 * 56) + ky * 7 + koff;
                        cy++;
                        float v0 = bf2f(sh[rt + ct[0]]);
                        float v1 = bf2f(sh[rt + ct[1]]);
                        float v2 = bf2f(sh[rt + ct[2]]);
                        sum += vx[0] ? v0 : 0.0f;
                        sum += vx[1] ? v1 : 0.0f;
                        sum += vx[2] ? v2 : 0.0f;
                    }
                }
                float fcy = (cy == 3) ? (1.0f / 3.0f) : ((cy == 2) ? 0.5f : 1.0f);
                float m = sum * fcx * fcy;
                val = 0.5f * m * (1.0f + erff(m * 0.70710678118654752f));  // exact gelu
            }
            sG[pr * 58 + pxl] = f2bf(val);
        }
    }
    __syncthreads();

    // phase 2: unfold sG -> g2 (magic-mul indices, no LUTs)
    {
        u16* g2row = g2 + (size_t)(n0 + o0 * 36 + 18 * xh) * HIDP + c0;
        for (int j = tid; j < 10 * 18 * 49; j += 512) {
            int l2 = (int)(((unsigned)j * 42800u) >> 21);
            int k  = j - l2 * 49;
            int oy = (int)(((unsigned)l2 * 57u) >> 10);
            int ox = l2 - 18 * oy;
            int ky = (int)(((unsigned)k * 37u) >> 8);
            int kx = k - 7 * ky;
            g2row[(size_t)(oy * 36 + ox) * HIDP + k] =
                sG[(3 * oy + ky) * 58 + 3 * ox + kx];
        }
    }
}

// ---------------- launch ----------------
extern "C" void kernel_launch(void* const* d_in, const int* in_sizes, int n_in,
                              void* d_out, int out_size, void* d_ws, size_t ws_size,
                              hipStream_t stream) {
    (void)in_sizes; (void)n_in; (void)out_size; (void)ws_size;
    const float* x  = (const float*)d_in[0];
    const float* W1 = (const float*)d_in[1];
    const float* b1 = (const float*)d_in[2];
    const float* W2 = (const float*)d_in[3];
    const float* b2 = (const float*)d_in[4];
    float* out = (float*)d_out;

    char* ws = (char*)d_ws;
    u16* xb  = (u16*)(ws);                       // 11520*512*2  = 11,796,480
    u16* W1b = (u16*)(ws + 11796480);            // 2048*512*2   =  2,097,152
    u16* W2b = (u16*)(ws + 13893632);            // 512*2048*2   =  2,097,152
    u16* hg  = (u16*)(ws + 15990784);            // 11520*2048*2 = 47,185,920
    u16* g2  = (u16*)(ws + 63176704);            // 11520*2048*2 = 47,185,920 (total 110 MB)

    // converts + g2 pad-zeroing (single dispatch)
    cvt_all<<<CVT_XB + CVT_W1B + CVT_W2B + CVT_Z, 256, 0, stream>>>(
        x, W1, W2, xb, W1b, W2b, g2);

    // GEMM1: 128x64 tiles, 256 threads, grid 90*32 = 2880, 6 blocks/CU
    gemm1_sm<<<(M_ROWS / 128) * (HIDP / 64), 256, 0, stream>>>(xb, W1b, b1, hg);

    // middle: fold/normalize/gelu/unfold fused, hg -> g2 (G stays in LDS)
    mid_fused<<<BPRIME * NCH * 4, 512, 0, stream>>>(hg, g2);

    // GEMM2: round-1 2-barrier 128x64 tiles, grid 90*8 = 720
    gemm2_bt<<<(M_ROWS / 128) * (DIM / 64), 512, 0, stream>>>(g2, W2b, b2, out);
}